// Round 1
// 12119.714 us; speedup vs baseline: 1.3811x; 1.3811x over previous
//
#include <hip/hip_runtime.h>

#define H 1024
#define EM 512
#define TSTEPS 2048
#define OSZ 32000
#define FOURH 4096
#define NWG 128

typedef __attribute__((ext_vector_type(8))) short short8;
typedef __attribute__((ext_vector_type(4))) float f32x4;

__device__ __forceinline__ unsigned short f2bf(float f) {
  union { float f; unsigned int u; } x; x.f = f;
  unsigned int r = x.u + 0x7FFFu + ((x.u >> 16) & 1u);   // RNE
  return (unsigned short)(r >> 16);
}
__device__ __forceinline__ unsigned int pk2(float lo, float hi) {
  return (unsigned int)f2bf(lo) | ((unsigned int)f2bf(hi) << 16);
}
__device__ __forceinline__ float fast_sigm(float x) {
  return __builtin_amdgcn_rcpf(1.0f + __expf(-x));
}
__device__ __forceinline__ float fast_tanh(float x) {
  // 1 - 2/(e^{2x}+1); exp->inf/0 endpoints saturate correctly to +/-1
  return 1.0f - 2.0f * __builtin_amdgcn_rcpf(1.0f + __expf(2.0f * x));
}

// ---------------- embedding gathers ----------------
__global__ void gather_k(const int* __restrict__ e1, const int* __restrict__ gt,
                         const float* __restrict__ emb_i, const float* __restrict__ emb_o,
                         float* __restrict__ enc_e, float* __restrict__ dec_e) {
  int row = blockIdx.x;
  int t4 = threadIdx.x * 4;
  if (blockIdx.y == 0) {
    int idx = e1[row];
    *(float4*)&enc_e[(size_t)row * EM + t4] = *(const float4*)&emb_i[(size_t)idx * EM + t4];
  } else {
    int idx = (row == 0) ? 1 : gt[row - 1];
    *(float4*)&dec_e[(size_t)row * EM + t4] = *(const float4*)&emb_o[(size_t)idx * EM + t4];
  }
}

// ------------- C[M,N] = A[M,K] @ B[N,K]^T + bias1 + bias2 (bf16 MFMA) -------------
#define LDT 40
__global__ __launch_bounds__(256) void gemm_bt(
    const float* __restrict__ A, const float* __restrict__ B,
    const float* __restrict__ bias1, const float* __restrict__ bias2,
    float* __restrict__ C, int M, int N, int K) {
  __shared__ __align__(16) unsigned short aL[64 * LDT];
  __shared__ __align__(16) unsigned short bL[64 * LDT];
  int tid = threadIdx.x;
  int n0 = blockIdx.x * 64, m0 = blockIdx.y * 64;
  int wv = tid >> 6, l = tid & 63;
  int wm = (wv >> 1) * 32, wn = (wv & 1) * 32;
  int col = l & 15, quad = l >> 4;
  f32x4 acc[2][2];
  acc[0][0] = (f32x4){0,0,0,0}; acc[0][1] = (f32x4){0,0,0,0};
  acc[1][0] = (f32x4){0,0,0,0}; acc[1][1] = (f32x4){0,0,0,0};

  int r = tid >> 2, c8 = (tid & 3) * 8;
  const float* ap = A + (size_t)(m0 + r) * K + c8;
  const float* bp = B + (size_t)(n0 + r) * K + c8;

  for (int k0 = 0; k0 < K; k0 += 32) {
    float4 a0 = *(const float4*)(ap + k0);
    float4 a1 = *(const float4*)(ap + k0 + 4);
    float4 b0 = *(const float4*)(bp + k0);
    float4 b1 = *(const float4*)(bp + k0 + 4);
    uint4 apk, bpk;
    apk.x = pk2(a0.x, a0.y); apk.y = pk2(a0.z, a0.w);
    apk.z = pk2(a1.x, a1.y); apk.w = pk2(a1.z, a1.w);
    bpk.x = pk2(b0.x, b0.y); bpk.y = pk2(b0.z, b0.w);
    bpk.z = pk2(b1.x, b1.y); bpk.w = pk2(b1.z, b1.w);
    *(uint4*)&aL[r * LDT + c8] = apk;
    *(uint4*)&bL[r * LDT + c8] = bpk;
    __syncthreads();

    short8 af0 = *(const short8*)&aL[(wm + col) * LDT + quad * 8];
    short8 af1 = *(const short8*)&aL[(wm + 16 + col) * LDT + quad * 8];
    short8 bf0 = *(const short8*)&bL[(wn + col) * LDT + quad * 8];
    short8 bf1 = *(const short8*)&bL[(wn + 16 + col) * LDT + quad * 8];
    acc[0][0] = __builtin_amdgcn_mfma_f32_16x16x32_bf16(af0, bf0, acc[0][0], 0, 0, 0);
    acc[0][1] = __builtin_amdgcn_mfma_f32_16x16x32_bf16(af0, bf1, acc[0][1], 0, 0, 0);
    acc[1][0] = __builtin_amdgcn_mfma_f32_16x16x32_bf16(af1, bf0, acc[1][0], 0, 0, 0);
    acc[1][1] = __builtin_amdgcn_mfma_f32_16x16x32_bf16(af1, bf1, acc[1][1], 0, 0, 0);
    __syncthreads();
  }

  #pragma unroll
  for (int j = 0; j < 2; ++j) {
    int n = n0 + wn + j * 16 + col;
    float b = (bias1 ? bias1[n] : 0.0f) + (bias2 ? bias2[n] : 0.0f);
    #pragma unroll
    for (int i = 0; i < 2; ++i) {
      #pragma unroll
      for (int rg = 0; rg < 4; ++rg) {
        int m = m0 + wm + i * 16 + quad * 4 + rg;
        C[(size_t)m * N + n] = acc[i][j][rg] + b;
      }
    }
  }
}

// ---------------- persistent LSTM recurrence ----------------
// 128 WGs x 256 thr. WG wg owns h indices [wg*8, wg*8+8). Wave w = gate w (i,f,g,o).
// Lane l: a=l>>4 handles gate rows {a, a+4}; q=l&15 handles INTERLEAVED cols
// {i*64 + q*4 .. +4 : i=0..15}  (2-way-free h_lds banks instead of 16-way).
// Whh slice LDS-resident (128 KB, lane-matched contiguous layout -> conflict-free).
// c in LDS. h exchanged via (fp32 value, canary=t+1) 8B agent-scope atomic pairs.
__global__ __launch_bounds__(256, 1) void lstm_k(
    const float* __restrict__ xg, const float* __restrict__ Whh,
    const float* __restrict__ h0c0, unsigned long long* __restrict__ pair,
    float* __restrict__ hs, float* __restrict__ c_out) {
  __shared__ __align__(16) float wlds[32768];   // 128 KB: this WG's 32 Whh rows
  __shared__ __align__(16) float h_lds[H];
  __shared__ float gate_lds[32];
  __shared__ float c_lds[8];
  int tid = threadIdx.x;
  int wg = blockIdx.x;
  int w = tid >> 6, l = tid & 63;
  int a = l >> 4, q = l & 15;
  int hbase = wg * 8;

  // ---- stage weights: float4 index idx4 = (((w*2+p)*16 + i)*4 + a)*16 + q ----
  // At step time, wave w / iter i / row-half p reads float4s (a*16+q) -> one
  // contiguous 1 KB block per wave-read => bank-conflict-free by construction.
  for (int idx4 = tid; idx4 < 8192; idx4 += 256) {
    int q_ = idx4 & 15;
    int a_ = (idx4 >> 4) & 3;
    int i_ = (idx4 >> 6) & 15;
    int p_ = (idx4 >> 10) & 1;
    int w_ = idx4 >> 11;
    int row = w_ * H + hbase + a_ + p_ * 4;
    int col = i_ * 64 + q_ * 4;
    *(float4*)&wlds[idx4 * 4] = *(const float4*)&Whh[(size_t)row * H + col];
  }
  for (int i = tid; i < H; i += 256) h_lds[i] = h0c0 ? h0c0[i] : 0.0f;
  if (tid < 8) c_lds[tid] = h0c0 ? h0c0[hbase + tid] : 0.0f;
  __syncthreads();

  const int wA_base = (((w * 2 + 0) * 16) * 4 + a) * 16 + q;  // float4 idx at i=0
  const int wB_base = (((w * 2 + 1) * 16) * 4 + a) * 16 + q;  // +64 float4 per i

  for (int t = 0; t < TSTEPS; ++t) {
    // prefetch this step's xg early (independent of h)
    float xgv = 0.0f;
    if (q < 2) xgv = xg[(size_t)t * FOURH + w * H + hbase + a + (q == 1 ? 4 : 0)];

    // partial matvec over this lane's interleaved 64 columns
    float sA0 = 0, sA1 = 0, sB0 = 0, sB1 = 0;
    #pragma unroll
    for (int i = 0; i < 16; ++i) {
      float4 hv = *(const float4*)&h_lds[i * 64 + q * 4];          // 2-way/bcast
      float4 wA = *(const float4*)&wlds[(wA_base + i * 64) * 4];   // contig 1KB
      float4 wB = *(const float4*)&wlds[(wB_base + i * 64) * 4];
      sA0 += wA.x * hv.x + wA.y * hv.y;
      sA1 += wA.z * hv.z + wA.w * hv.w;
      sB0 += wB.x * hv.x + wB.y * hv.y;
      sB1 += wB.z * hv.z + wB.w * hv.w;
    }
    float accA = sA0 + sA1, accB = sB0 + sB1;
    // reduce across the 16 col-chunks (lane bits 0..3)
    #pragma unroll
    for (int s = 1; s < 16; s <<= 1) {
      accA += __shfl_xor(accA, s);
      accB += __shfl_xor(accB, s);
    }
    if (q == 0)      gate_lds[w * 8 + a]     = accA + xgv;
    else if (q == 1) gate_lds[w * 8 + a + 4] = accB + xgv;
    __syncthreads();

    if (tid < 8) {
      int j = tid;
      float gi = gate_lds[j], gf = gate_lds[8 + j], gg = gate_lds[16 + j], go = gate_lds[24 + j];
      float c = fast_sigm(gf) * c_lds[j] + fast_sigm(gi) * fast_tanh(gg);
      float h = fast_sigm(go) * fast_tanh(c);
      c_lds[j] = c;
      unsigned long long pkd = (unsigned long long)__float_as_uint(h) |
                               ((unsigned long long)(unsigned int)(t + 1) << 32);
      __hip_atomic_store(&pair[(size_t)t * H + hbase + j], pkd,
                         __ATOMIC_RELAXED, __HIP_MEMORY_SCOPE_AGENT);
      if (hs) hs[(size_t)t * H + hbase + j] = h;
    }

    if (t + 1 < TSTEPS) {
      int base = tid * 4;
      const unsigned long long* src = pair + (size_t)t * H + base;
      unsigned int want = (unsigned int)(t + 1);
      float v[4]; unsigned int done = 0;
      while (done != 0xFu) {
        #pragma unroll
        for (int i = 0; i < 4; ++i) {
          if (!(done & (1u << i))) {
            unsigned long long p = __hip_atomic_load(&src[i], __ATOMIC_RELAXED,
                                                     __HIP_MEMORY_SCOPE_AGENT);
            if ((unsigned int)(p >> 32) == want) {
              v[i] = __uint_as_float((unsigned int)p);
              done |= (1u << i);
            }
          }
        }
      }
      h_lds[base] = v[0]; h_lds[base + 1] = v[1];
      h_lds[base + 2] = v[2]; h_lds[base + 3] = v[3];
    }
    __syncthreads();
  }
  if (c_out && tid < 8) c_out[hbase + tid] = c_lds[tid];
}

extern "C" void kernel_launch(void* const* d_in, const int* in_sizes, int n_in,
                              void* d_out, int out_size, void* d_ws, size_t ws_size,
                              hipStream_t stream) {
  const int*   e1      = (const int*)d_in[0];
  const int*   gt      = (const int*)d_in[1];
  const float* emb_i   = (const float*)d_in[2];
  const float* emb_o   = (const float*)d_in[3];
  const float* enc_Wih = (const float*)d_in[4];
  const float* enc_Whh = (const float*)d_in[5];
  const float* enc_bih = (const float*)d_in[6];
  const float* enc_bhh = (const float*)d_in[7];
  const float* dec_Wih = (const float*)d_in[8];
  const float* dec_Whh = (const float*)d_in[9];
  const float* dec_bih = (const float*)d_in[10];
  const float* dec_bhh = (const float*)d_in[11];
  const float* outW    = (const float*)d_in[12];
  const float* outb    = (const float*)d_in[13];
  float* out = (float*)d_out;

  char* ws = (char*)d_ws;
  size_t off = 0;
  float* enc_embs = (float*)(ws + off); off += (size_t)TSTEPS * EM * 4;        // 4 MB
  float* dec_embs = (float*)(ws + off); off += (size_t)TSTEPS * EM * 4;        // 4 MB
  float* xg_enc   = (float*)(ws + off); off += (size_t)TSTEPS * FOURH * 4;     // 33.5 MB
  float* xg_dec   = (float*)(ws + off); off += (size_t)TSTEPS * FOURH * 4;     // 33.5 MB
  unsigned long long* pair_enc = (unsigned long long*)(ws + off); off += (size_t)TSTEPS * H * 8;  // 16.8 MB
  unsigned long long* pair_dec = (unsigned long long*)(ws + off); off += (size_t)TSTEPS * H * 8;  // 16.8 MB
  float* enc_c = (float*)(ws + off);    off += (size_t)H * 4;
  float* hs    = (float*)(ws + off);    off += (size_t)TSTEPS * H * 4;         // 8.4 MB

  // 1. embedding gathers
  gather_k<<<dim3(TSTEPS, 2), 128, 0, stream>>>(e1, gt, emb_i, emb_o, enc_embs, dec_embs);
  // 2. encoder x_gates: [2048,512] @ [4096,512]^T + (bih+bhh)
  gemm_bt<<<dim3(FOURH / 64, TSTEPS / 64), 256, 0, stream>>>(
      enc_embs, enc_Wih, enc_bih, enc_bhh, xg_enc, TSTEPS, FOURH, EM);
  // 3. encoder recurrence -> enc_c
  lstm_k<<<NWG, 256, 0, stream>>>(xg_enc, enc_Whh, nullptr, pair_enc, nullptr, enc_c);
  // 4. decoder x_gates
  gemm_bt<<<dim3(FOURH / 64, TSTEPS / 64), 256, 0, stream>>>(
      dec_embs, dec_Wih, dec_bih, dec_bhh, xg_dec, TSTEPS, FOURH, EM);
  // 5. decoder recurrence -> hs
  lstm_k<<<NWG, 256, 0, stream>>>(xg_dec, dec_Whh, enc_c, pair_dec, hs, nullptr);
  // 6. logits: [2048,1024] @ [32000,1024]^T + outb
  gemm_bt<<<dim3(OSZ / 64, TSTEPS / 64), 256, 0, stream>>>(
      hs, outW, outb, nullptr, out, TSTEPS, OSZ, H);
}

// Round 2
// 11293.627 us; speedup vs baseline: 1.4821x; 1.0731x over previous
//
#include <hip/hip_runtime.h>

#define H 1024
#define EM 512
#define TSTEPS 2048
#define OSZ 32000
#define FOURH 4096
#define NWG 128

typedef __attribute__((ext_vector_type(8))) short short8;
typedef __attribute__((ext_vector_type(4))) float f32x4;

__device__ __forceinline__ unsigned short f2bf(float f) {
  union { float f; unsigned int u; } x; x.f = f;
  unsigned int r = x.u + 0x7FFFu + ((x.u >> 16) & 1u);   // RNE
  return (unsigned short)(r >> 16);
}
__device__ __forceinline__ unsigned int pk2(float lo, float hi) {
  return (unsigned int)f2bf(lo) | ((unsigned int)f2bf(hi) << 16);
}
__device__ __forceinline__ float fast_sigm(float x) {
  return __builtin_amdgcn_rcpf(1.0f + __expf(-x));
}
__device__ __forceinline__ float fast_tanh(float x) {
  // 1 - 2/(e^{2x}+1); exp->inf/0 endpoints saturate correctly to +/-1
  return 1.0f - 2.0f * __builtin_amdgcn_rcpf(1.0f + __expf(2.0f * x));
}

// ---------------- embedding gathers ----------------
__global__ void gather_k(const int* __restrict__ e1, const int* __restrict__ gt,
                         const float* __restrict__ emb_i, const float* __restrict__ emb_o,
                         float* __restrict__ enc_e, float* __restrict__ dec_e) {
  int row = blockIdx.x;
  int t4 = threadIdx.x * 4;
  if (blockIdx.y == 0) {
    int idx = e1[row];
    *(float4*)&enc_e[(size_t)row * EM + t4] = *(const float4*)&emb_i[(size_t)idx * EM + t4];
  } else {
    int idx = (row == 0) ? 1 : gt[row - 1];
    *(float4*)&dec_e[(size_t)row * EM + t4] = *(const float4*)&emb_o[(size_t)idx * EM + t4];
  }
}

// ------------- C[M,N] = A[M,K] @ B[N,K]^T + bias1 + bias2 (bf16 MFMA) -------------
#define LDT 40
__global__ __launch_bounds__(256) void gemm_bt(
    const float* __restrict__ A, const float* __restrict__ B,
    const float* __restrict__ bias1, const float* __restrict__ bias2,
    float* __restrict__ C, int M, int N, int K) {
  __shared__ __align__(16) unsigned short aL[64 * LDT];
  __shared__ __align__(16) unsigned short bL[64 * LDT];
  int tid = threadIdx.x;
  int n0 = blockIdx.x * 64, m0 = blockIdx.y * 64;
  int wv = tid >> 6, l = tid & 63;
  int wm = (wv >> 1) * 32, wn = (wv & 1) * 32;
  int col = l & 15, quad = l >> 4;
  f32x4 acc[2][2];
  acc[0][0] = (f32x4){0,0,0,0}; acc[0][1] = (f32x4){0,0,0,0};
  acc[1][0] = (f32x4){0,0,0,0}; acc[1][1] = (f32x4){0,0,0,0};

  int r = tid >> 2, c8 = (tid & 3) * 8;
  const float* ap = A + (size_t)(m0 + r) * K + c8;
  const float* bp = B + (size_t)(n0 + r) * K + c8;

  for (int k0 = 0; k0 < K; k0 += 32) {
    float4 a0 = *(const float4*)(ap + k0);
    float4 a1 = *(const float4*)(ap + k0 + 4);
    float4 b0 = *(const float4*)(bp + k0);
    float4 b1 = *(const float4*)(bp + k0 + 4);
    uint4 apk, bpk;
    apk.x = pk2(a0.x, a0.y); apk.y = pk2(a0.z, a0.w);
    apk.z = pk2(a1.x, a1.y); apk.w = pk2(a1.z, a1.w);
    bpk.x = pk2(b0.x, b0.y); bpk.y = pk2(b0.z, b0.w);
    bpk.z = pk2(b1.x, b1.y); bpk.w = pk2(b1.z, b1.w);
    *(uint4*)&aL[r * LDT + c8] = apk;
    *(uint4*)&bL[r * LDT + c8] = bpk;
    __syncthreads();

    short8 af0 = *(const short8*)&aL[(wm + col) * LDT + quad * 8];
    short8 af1 = *(const short8*)&aL[(wm + 16 + col) * LDT + quad * 8];
    short8 bf0 = *(const short8*)&bL[(wn + col) * LDT + quad * 8];
    short8 bf1 = *(const short8*)&bL[(wn + 16 + col) * LDT + quad * 8];
    acc[0][0] = __builtin_amdgcn_mfma_f32_16x16x32_bf16(af0, bf0, acc[0][0], 0, 0, 0);
    acc[0][1] = __builtin_amdgcn_mfma_f32_16x16x32_bf16(af0, bf1, acc[0][1], 0, 0, 0);
    acc[1][0] = __builtin_amdgcn_mfma_f32_16x16x32_bf16(af1, bf0, acc[1][0], 0, 0, 0);
    acc[1][1] = __builtin_amdgcn_mfma_f32_16x16x32_bf16(af1, bf1, acc[1][1], 0, 0, 0);
    __syncthreads();
  }

  #pragma unroll
  for (int j = 0; j < 2; ++j) {
    int n = n0 + wn + j * 16 + col;
    float b = (bias1 ? bias1[n] : 0.0f) + (bias2 ? bias2[n] : 0.0f);
    #pragma unroll
    for (int i = 0; i < 2; ++i) {
      #pragma unroll
      for (int rg = 0; rg < 4; ++rg) {
        int m = m0 + wm + i * 16 + quad * 4 + rg;
        C[(size_t)m * N + n] = acc[i][j][rg] + b;
      }
    }
  }
}

// ---------------- persistent LSTM recurrence ----------------
// 128 WGs x 256 thr. WG wg owns h indices [wg*8, wg*8+8). Wave w = gate w (i,f,g,o).
// Lane l: a=l>>4 handles gate rows {a, a+4}; q=l&15 handles INTERLEAVED cols
// {i*64 + q*4 .. +4 : i=0..15}.
// Whh slice REGISTER-resident: 32 named f32x4 (128 VGPRs/lane), loaded once from
// global (coalesced per 16-lane group) and pinned with an empty asm so the
// allocator cannot spill/remat them inside the t-loop. h_lds reads 2-way/bcast.
// c in LDS. h exchanged via (fp32 value, canary=t+1) 8B agent-scope atomic pairs.
__global__ __launch_bounds__(256, 1) void lstm_k(
    const float* __restrict__ xg, const float* __restrict__ Whh,
    const float* __restrict__ h0c0, unsigned long long* __restrict__ pair,
    float* __restrict__ hs, float* __restrict__ c_out) {
  __shared__ __align__(16) float h_lds[H];
  __shared__ float gate_lds[32];
  __shared__ float c_lds[8];
  int tid = threadIdx.x;
  int wg = blockIdx.x;
  int w = tid >> 6, l = tid & 63;
  int a = l >> 4, q = l & 15;
  int q4 = q * 4;
  int hbase = wg * 8;
  int rowA = w * H + hbase + a;
  int rowB = rowA + 4;

  // ---- register-resident Whh slice: 16 f32x4 per row, rows A and B ----
  const float* wpA = Whh + (size_t)rowA * H + q4;
  const float* wpB = Whh + (size_t)rowB * H + q4;
#define LOADW(i) \
  f32x4 wA##i = *(const f32x4*)(wpA + (i) * 64); \
  f32x4 wB##i = *(const f32x4*)(wpB + (i) * 64);
  LOADW(0)  LOADW(1)  LOADW(2)  LOADW(3)
  LOADW(4)  LOADW(5)  LOADW(6)  LOADW(7)
  LOADW(8)  LOADW(9)  LOADW(10) LOADW(11)
  LOADW(12) LOADW(13) LOADW(14) LOADW(15)
#undef LOADW
  // pin: opaque producer -> no remat, must stay in VGPRs (budget 512 @ 1 wave/EU)
  asm volatile("" : "+v"(wA0), "+v"(wA1), "+v"(wA2), "+v"(wA3),
                    "+v"(wA4), "+v"(wA5), "+v"(wA6), "+v"(wA7));
  asm volatile("" : "+v"(wA8), "+v"(wA9), "+v"(wA10), "+v"(wA11),
                    "+v"(wA12), "+v"(wA13), "+v"(wA14), "+v"(wA15));
  asm volatile("" : "+v"(wB0), "+v"(wB1), "+v"(wB2), "+v"(wB3),
                    "+v"(wB4), "+v"(wB5), "+v"(wB6), "+v"(wB7));
  asm volatile("" : "+v"(wB8), "+v"(wB9), "+v"(wB10), "+v"(wB11),
                    "+v"(wB12), "+v"(wB13), "+v"(wB14), "+v"(wB15));

  for (int i = tid; i < H; i += 256) h_lds[i] = h0c0 ? h0c0[i] : 0.0f;
  if (tid < 8) c_lds[tid] = h0c0 ? h0c0[hbase + tid] : 0.0f;
  __syncthreads();

  for (int t = 0; t < TSTEPS; ++t) {
    // prefetch this step's xg early (independent of h)
    float xgv = 0.0f;
    if (q < 2) xgv = xg[(size_t)t * FOURH + w * H + hbase + a + (q == 1 ? 4 : 0)];

    // partial matvec over this lane's interleaved 64 columns
    float sA0 = 0, sA1 = 0, sB0 = 0, sB1 = 0;
#define FMA(i) { \
    f32x4 hv = *(const f32x4*)&h_lds[(i) * 64 + q4]; \
    sA0 += wA##i.x * hv.x + wA##i.y * hv.y; \
    sA1 += wA##i.z * hv.z + wA##i.w * hv.w; \
    sB0 += wB##i.x * hv.x + wB##i.y * hv.y; \
    sB1 += wB##i.z * hv.z + wB##i.w * hv.w; }
    FMA(0)  FMA(1)  FMA(2)  FMA(3)
    FMA(4)  FMA(5)  FMA(6)  FMA(7)
    FMA(8)  FMA(9)  FMA(10) FMA(11)
    FMA(12) FMA(13) FMA(14) FMA(15)
#undef FMA
    float accA = sA0 + sA1, accB = sB0 + sB1;
    // reduce across the 16 col-chunks (lane bits 0..3)
    #pragma unroll
    for (int s = 1; s < 16; s <<= 1) {
      accA += __shfl_xor(accA, s);
      accB += __shfl_xor(accB, s);
    }
    if (q == 0)      gate_lds[w * 8 + a]     = accA + xgv;
    else if (q == 1) gate_lds[w * 8 + a + 4] = accB + xgv;
    __syncthreads();

    if (tid < 8) {
      int j = tid;
      float gi = gate_lds[j], gf = gate_lds[8 + j], gg = gate_lds[16 + j], go = gate_lds[24 + j];
      float c = fast_sigm(gf) * c_lds[j] + fast_sigm(gi) * fast_tanh(gg);
      float h = fast_sigm(go) * fast_tanh(c);
      c_lds[j] = c;
      unsigned long long pkd = (unsigned long long)__float_as_uint(h) |
                               ((unsigned long long)(unsigned int)(t + 1) << 32);
      __hip_atomic_store(&pair[(size_t)t * H + hbase + j], pkd,
                         __ATOMIC_RELAXED, __HIP_MEMORY_SCOPE_AGENT);
      if (hs) hs[(size_t)t * H + hbase + j] = h;
    }

    if (t + 1 < TSTEPS) {
      int base = tid * 4;
      const unsigned long long* src = pair + (size_t)t * H + base;
      unsigned int want = (unsigned int)(t + 1);
      float v[4]; unsigned int done = 0;
      while (done != 0xFu) {
        #pragma unroll
        for (int i = 0; i < 4; ++i) {
          if (!(done & (1u << i))) {
            unsigned long long p = __hip_atomic_load(&src[i], __ATOMIC_RELAXED,
                                                     __HIP_MEMORY_SCOPE_AGENT);
            if ((unsigned int)(p >> 32) == want) {
              v[i] = __uint_as_float((unsigned int)p);
              done |= (1u << i);
            }
          }
        }
      }
      h_lds[base] = v[0]; h_lds[base + 1] = v[1];
      h_lds[base + 2] = v[2]; h_lds[base + 3] = v[3];
    }
    __syncthreads();
  }
  if (c_out && tid < 8) c_out[hbase + tid] = c_lds[tid];
}

extern "C" void kernel_launch(void* const* d_in, const int* in_sizes, int n_in,
                              void* d_out, int out_size, void* d_ws, size_t ws_size,
                              hipStream_t stream) {
  const int*   e1      = (const int*)d_in[0];
  const int*   gt      = (const int*)d_in[1];
  const float* emb_i   = (const float*)d_in[2];
  const float* emb_o   = (const float*)d_in[3];
  const float* enc_Wih = (const float*)d_in[4];
  const float* enc_Whh = (const float*)d_in[5];
  const float* enc_bih = (const float*)d_in[6];
  const float* enc_bhh = (const float*)d_in[7];
  const float* dec_Wih = (const float*)d_in[8];
  const float* dec_Whh = (const float*)d_in[9];
  const float* dec_bih = (const float*)d_in[10];
  const float* dec_bhh = (const float*)d_in[11];
  const float* outW    = (const float*)d_in[12];
  const float* outb    = (const float*)d_in[13];
  float* out = (float*)d_out;

  char* ws = (char*)d_ws;
  size_t off = 0;
  float* enc_embs = (float*)(ws + off); off += (size_t)TSTEPS * EM * 4;        // 4 MB
  float* dec_embs = (float*)(ws + off); off += (size_t)TSTEPS * EM * 4;        // 4 MB
  float* xg_enc   = (float*)(ws + off); off += (size_t)TSTEPS * FOURH * 4;     // 33.5 MB
  float* xg_dec   = (float*)(ws + off); off += (size_t)TSTEPS * FOURH * 4;     // 33.5 MB
  unsigned long long* pair_enc = (unsigned long long*)(ws + off); off += (size_t)TSTEPS * H * 8;  // 16.8 MB
  unsigned long long* pair_dec = (unsigned long long*)(ws + off); off += (size_t)TSTEPS * H * 8;  // 16.8 MB
  float* enc_c = (float*)(ws + off);    off += (size_t)H * 4;
  float* hs    = (float*)(ws + off);    off += (size_t)TSTEPS * H * 4;         // 8.4 MB

  // 1. embedding gathers
  gather_k<<<dim3(TSTEPS, 2), 128, 0, stream>>>(e1, gt, emb_i, emb_o, enc_embs, dec_embs);
  // 2. encoder x_gates: [2048,512] @ [4096,512]^T + (bih+bhh)
  gemm_bt<<<dim3(FOURH / 64, TSTEPS / 64), 256, 0, stream>>>(
      enc_embs, enc_Wih, enc_bih, enc_bhh, xg_enc, TSTEPS, FOURH, EM);
  // 3. encoder recurrence -> enc_c
  lstm_k<<<NWG, 256, 0, stream>>>(xg_enc, enc_Whh, nullptr, pair_enc, nullptr, enc_c);
  // 4. decoder x_gates
  gemm_bt<<<dim3(FOURH / 64, TSTEPS / 64), 256, 0, stream>>>(
      dec_embs, dec_Wih, dec_bih, dec_bhh, xg_dec, TSTEPS, FOURH, EM);
  // 5. decoder recurrence -> hs
  lstm_k<<<NWG, 256, 0, stream>>>(xg_dec, dec_Whh, enc_c, pair_dec, hs, nullptr);
  // 6. logits: [2048,1024] @ [32000,1024]^T + outb
  gemm_bt<<<dim3(OSZ / 64, TSTEPS / 64), 256, 0, stream>>>(
      hs, outW, outb, nullptr, out, TSTEPS, OSZ, H);
}

// Round 3
// 10916.266 us; speedup vs baseline: 1.5333x; 1.0346x over previous
//
#include <hip/hip_runtime.h>

#define H 1024
#define EM 512
#define TSTEPS 2048
#define OSZ 32000
#define FOURH 4096
#define NWG 128

typedef __attribute__((ext_vector_type(8))) short short8;
typedef __attribute__((ext_vector_type(4))) float f32x4;

__device__ __forceinline__ unsigned short f2bf(float f) {
  union { float f; unsigned int u; } x; x.f = f;
  unsigned int r = x.u + 0x7FFFu + ((x.u >> 16) & 1u);   // RNE
  return (unsigned short)(r >> 16);
}
__device__ __forceinline__ unsigned int pk2(float lo, float hi) {
  return (unsigned int)f2bf(lo) | ((unsigned int)f2bf(hi) << 16);
}
__device__ __forceinline__ float fast_sigm(float x) {
  return __builtin_amdgcn_rcpf(1.0f + __expf(-x));
}
__device__ __forceinline__ float fast_tanh(float x) {
  // 1 - 2/(e^{2x}+1); exp->inf/0 endpoints saturate correctly to +/-1
  return 1.0f - 2.0f * __builtin_amdgcn_rcpf(1.0f + __expf(2.0f * x));
}

// DPP all-reduce (sum) within each 16-lane row: xor1, xor2, ror4, ror8.
// Pure VALU (no LDS pipe), ~4x lower latency than ds_swizzle shuffles.
#define DPP_ADD(x, ctrl) \
  ((x) + __int_as_float(__builtin_amdgcn_update_dpp( \
       0, __float_as_int(x), (ctrl), 0xf, 0xf, true)))

// ---------------- embedding gathers ----------------
__global__ void gather_k(const int* __restrict__ e1, const int* __restrict__ gt,
                         const float* __restrict__ emb_i, const float* __restrict__ emb_o,
                         float* __restrict__ enc_e, float* __restrict__ dec_e) {
  int row = blockIdx.x;
  int t4 = threadIdx.x * 4;
  if (blockIdx.y == 0) {
    int idx = e1[row];
    *(float4*)&enc_e[(size_t)row * EM + t4] = *(const float4*)&emb_i[(size_t)idx * EM + t4];
  } else {
    int idx = (row == 0) ? 1 : gt[row - 1];
    *(float4*)&dec_e[(size_t)row * EM + t4] = *(const float4*)&emb_o[(size_t)idx * EM + t4];
  }
}

// ------------- C[M,N] = A[M,K] @ B[N,K]^T + bias1 + bias2 (bf16 MFMA) -------------
#define LDT 40
__global__ __launch_bounds__(256) void gemm_bt(
    const float* __restrict__ A, const float* __restrict__ B,
    const float* __restrict__ bias1, const float* __restrict__ bias2,
    float* __restrict__ C, int M, int N, int K) {
  __shared__ __align__(16) unsigned short aL[64 * LDT];
  __shared__ __align__(16) unsigned short bL[64 * LDT];
  int tid = threadIdx.x;
  int n0 = blockIdx.x * 64, m0 = blockIdx.y * 64;
  int wv = tid >> 6, l = tid & 63;
  int wm = (wv >> 1) * 32, wn = (wv & 1) * 32;
  int col = l & 15, quad = l >> 4;
  f32x4 acc[2][2];
  acc[0][0] = (f32x4){0,0,0,0}; acc[0][1] = (f32x4){0,0,0,0};
  acc[1][0] = (f32x4){0,0,0,0}; acc[1][1] = (f32x4){0,0,0,0};

  int r = tid >> 2, c8 = (tid & 3) * 8;
  const float* ap = A + (size_t)(m0 + r) * K + c8;
  const float* bp = B + (size_t)(n0 + r) * K + c8;

  for (int k0 = 0; k0 < K; k0 += 32) {
    float4 a0 = *(const float4*)(ap + k0);
    float4 a1 = *(const float4*)(ap + k0 + 4);
    float4 b0 = *(const float4*)(bp + k0);
    float4 b1 = *(const float4*)(bp + k0 + 4);
    uint4 apk, bpk;
    apk.x = pk2(a0.x, a0.y); apk.y = pk2(a0.z, a0.w);
    apk.z = pk2(a1.x, a1.y); apk.w = pk2(a1.z, a1.w);
    bpk.x = pk2(b0.x, b0.y); bpk.y = pk2(b0.z, b0.w);
    bpk.z = pk2(b1.x, b1.y); bpk.w = pk2(b1.z, b1.w);
    *(uint4*)&aL[r * LDT + c8] = apk;
    *(uint4*)&bL[r * LDT + c8] = bpk;
    __syncthreads();

    short8 af0 = *(const short8*)&aL[(wm + col) * LDT + quad * 8];
    short8 af1 = *(const short8*)&aL[(wm + 16 + col) * LDT + quad * 8];
    short8 bf0 = *(const short8*)&bL[(wn + col) * LDT + quad * 8];
    short8 bf1 = *(const short8*)&bL[(wn + 16 + col) * LDT + quad * 8];
    acc[0][0] = __builtin_amdgcn_mfma_f32_16x16x32_bf16(af0, bf0, acc[0][0], 0, 0, 0);
    acc[0][1] = __builtin_amdgcn_mfma_f32_16x16x32_bf16(af0, bf1, acc[0][1], 0, 0, 0);
    acc[1][0] = __builtin_amdgcn_mfma_f32_16x16x32_bf16(af1, bf0, acc[1][0], 0, 0, 0);
    acc[1][1] = __builtin_amdgcn_mfma_f32_16x16x32_bf16(af1, bf1, acc[1][1], 0, 0, 0);
    __syncthreads();
  }

  #pragma unroll
  for (int j = 0; j < 2; ++j) {
    int n = n0 + wn + j * 16 + col;
    float b = (bias1 ? bias1[n] : 0.0f) + (bias2 ? bias2[n] : 0.0f);
    #pragma unroll
    for (int i = 0; i < 2; ++i) {
      #pragma unroll
      for (int rg = 0; rg < 4; ++rg) {
        int m = m0 + wm + i * 16 + quad * 4 + rg;
        C[(size_t)m * N + n] = acc[i][j][rg] + b;
      }
    }
  }
}

// ---------------- persistent LSTM recurrence ----------------
// 128 WGs x 256 thr. WG wg owns h indices [wg*8, wg*8+8). Wave w = gate w (i,f,g,o).
// Lane l: a=l>>4 handles gate rows {a, a+4}; q=l&15 handles INTERLEAVED cols
// {i*64 + q*4 .. +4 : i=0..15}.
// Whh slice register-resident (32 named f32x4, pinned; allocator uses AGPRs).
// Critical-path design: xg prefetched one step ahead (HBM latency hidden);
// gate activations applied WAVE-PARALLEL before the LDS exchange; reduce via
// DPP (VALU) not ds_swizzle. h exchanged via (fp32, canary=t+1) 8B agent atomics.
__global__ __launch_bounds__(256, 1) void lstm_k(
    const float* __restrict__ xg, const float* __restrict__ Whh,
    const float* __restrict__ h0c0, unsigned long long* __restrict__ pair,
    float* __restrict__ hs, float* __restrict__ c_out) {
  __shared__ __align__(16) float h_lds[H];
  __shared__ float gate_lds[32];
  __shared__ float c_lds[8];
  int tid = threadIdx.x;
  int wg = blockIdx.x;
  int w = tid >> 6, l = tid & 63;
  int a = l >> 4, q = l & 15;
  int q4 = q * 4;
  int hbase = wg * 8;
  int rowA = w * H + hbase + a;
  int rowB = rowA + 4;

  // ---- register-resident Whh slice: 16 f32x4 per row, rows A and B ----
  const float* wpA = Whh + (size_t)rowA * H + q4;
  const float* wpB = Whh + (size_t)rowB * H + q4;
#define LOADW(i) \
  f32x4 wA##i = *(const f32x4*)(wpA + (i) * 64); \
  f32x4 wB##i = *(const f32x4*)(wpB + (i) * 64);
  LOADW(0)  LOADW(1)  LOADW(2)  LOADW(3)
  LOADW(4)  LOADW(5)  LOADW(6)  LOADW(7)
  LOADW(8)  LOADW(9)  LOADW(10) LOADW(11)
  LOADW(12) LOADW(13) LOADW(14) LOADW(15)
#undef LOADW
  // pin: opaque producer -> no remat/spill (unified VGPR/AGPR file, 1 wave/EU)
  asm volatile("" : "+v"(wA0), "+v"(wA1), "+v"(wA2), "+v"(wA3),
                    "+v"(wA4), "+v"(wA5), "+v"(wA6), "+v"(wA7));
  asm volatile("" : "+v"(wA8), "+v"(wA9), "+v"(wA10), "+v"(wA11),
                    "+v"(wA12), "+v"(wA13), "+v"(wA14), "+v"(wA15));
  asm volatile("" : "+v"(wB0), "+v"(wB1), "+v"(wB2), "+v"(wB3),
                    "+v"(wB4), "+v"(wB5), "+v"(wB6), "+v"(wB7));
  asm volatile("" : "+v"(wB8), "+v"(wB9), "+v"(wB10), "+v"(wB11),
                    "+v"(wB12), "+v"(wB13), "+v"(wB14), "+v"(wB15));

  for (int i = tid; i < H; i += 256) h_lds[i] = h0c0 ? h0c0[i] : 0.0f;
  if (tid < 8) c_lds[tid] = h0c0 ? h0c0[hbase + tid] : 0.0f;
  __syncthreads();

  // xg pointer for this lane's gate element (q==0 -> row a, q==1 -> row a+4)
  const float* xgp = xg + w * H + hbase + a + (q == 1 ? 4 : 0);
  float xgv_next = (q < 2) ? xgp[0] : 0.0f;   // prefetch t=0

  for (int t = 0; t < TSTEPS; ++t) {
    float xgv = xgv_next;
    // issue t+1's xg load now; consumed a full step later -> HBM latency hidden
    if (q < 2 && t + 1 < TSTEPS) xgv_next = xgp[(size_t)(t + 1) * FOURH];

    // partial matvec over this lane's interleaved 64 columns
    float sA0 = 0, sA1 = 0, sB0 = 0, sB1 = 0;
#define FMA(i) { \
    f32x4 hv = *(const f32x4*)&h_lds[(i) * 64 + q4]; \
    sA0 += wA##i.x * hv.x + wA##i.y * hv.y; \
    sA1 += wA##i.z * hv.z + wA##i.w * hv.w; \
    sB0 += wB##i.x * hv.x + wB##i.y * hv.y; \
    sB1 += wB##i.z * hv.z + wB##i.w * hv.w; }
    FMA(0)  FMA(1)  FMA(2)  FMA(3)
    FMA(4)  FMA(5)  FMA(6)  FMA(7)
    FMA(8)  FMA(9)  FMA(10) FMA(11)
    FMA(12) FMA(13) FMA(14) FMA(15)
#undef FMA
    float accA = sA0 + sA1, accB = sB0 + sB1;
    // DPP all-reduce across the 16 col-chunk lanes (within each 16-lane row)
    accA = DPP_ADD(accA, 0xB1);  accB = DPP_ADD(accB, 0xB1);   // quad_perm xor1
    accA = DPP_ADD(accA, 0x4E);  accB = DPP_ADD(accB, 0x4E);   // quad_perm xor2
    accA = DPP_ADD(accA, 0x124); accB = DPP_ADD(accB, 0x124);  // row_ror:4
    accA = DPP_ADD(accA, 0x128); accB = DPP_ADD(accB, 0x128);  // row_ror:8

    // wave-parallel activation BEFORE the exchange (w uniform -> no divergence)
    float gv = ((q == 0) ? accA : accB) + xgv;
    float act = (w == 2) ? fast_tanh(gv) : fast_sigm(gv);
    if (q == 0)      gate_lds[w * 8 + a]     = act;
    else if (q == 1) gate_lds[w * 8 + a + 4] = act;
    __syncthreads();

    if (tid < 8) {
      int j = tid;
      float gi = gate_lds[j], gf = gate_lds[8 + j], gg = gate_lds[16 + j], go = gate_lds[24 + j];
      float c = gf * c_lds[j] + gi * gg;          // gates pre-activated
      float h = go * fast_tanh(c);
      c_lds[j] = c;
      unsigned long long pkd = (unsigned long long)__float_as_uint(h) |
                               ((unsigned long long)(unsigned int)(t + 1) << 32);
      __hip_atomic_store(&pair[(size_t)t * H + hbase + j], pkd,
                         __ATOMIC_RELAXED, __HIP_MEMORY_SCOPE_AGENT);
      if (hs) hs[(size_t)t * H + hbase + j] = h;
    }

    if (t + 1 < TSTEPS) {
      int base = tid * 4;
      const unsigned long long* src = pair + (size_t)t * H + base;
      unsigned int want = (unsigned int)(t + 1);
      float v[4]; unsigned int done = 0;
      while (done != 0xFu) {
        #pragma unroll
        for (int i = 0; i < 4; ++i) {
          if (!(done & (1u << i))) {
            unsigned long long p = __hip_atomic_load(&src[i], __ATOMIC_RELAXED,
                                                     __HIP_MEMORY_SCOPE_AGENT);
            if ((unsigned int)(p >> 32) == want) {
              v[i] = __uint_as_float((unsigned int)p);
              done |= (1u << i);
            }
          }
        }
      }
      h_lds[base] = v[0]; h_lds[base + 1] = v[1];
      h_lds[base + 2] = v[2]; h_lds[base + 3] = v[3];
    }
    __syncthreads();
  }
  if (c_out && tid < 8) c_out[hbase + tid] = c_lds[tid];
}

extern "C" void kernel_launch(void* const* d_in, const int* in_sizes, int n_in,
                              void* d_out, int out_size, void* d_ws, size_t ws_size,
                              hipStream_t stream) {
  const int*   e1      = (const int*)d_in[0];
  const int*   gt      = (const int*)d_in[1];
  const float* emb_i   = (const float*)d_in[2];
  const float* emb_o   = (const float*)d_in[3];
  const float* enc_Wih = (const float*)d_in[4];
  const float* enc_Whh = (const float*)d_in[5];
  const float* enc_bih = (const float*)d_in[6];
  const float* enc_bhh = (const float*)d_in[7];
  const float* dec_Wih = (const float*)d_in[8];
  const float* dec_Whh = (const float*)d_in[9];
  const float* dec_bih = (const float*)d_in[10];
  const float* dec_bhh = (const float*)d_in[11];
  const float* outW    = (const float*)d_in[12];
  const float* outb    = (const float*)d_in[13];
  float* out = (float*)d_out;

  char* ws = (char*)d_ws;
  size_t off = 0;
  float* enc_embs = (float*)(ws + off); off += (size_t)TSTEPS * EM * 4;        // 4 MB
  float* dec_embs = (float*)(ws + off); off += (size_t)TSTEPS * EM * 4;        // 4 MB
  float* xg_enc   = (float*)(ws + off); off += (size_t)TSTEPS * FOURH * 4;     // 33.5 MB
  float* xg_dec   = (float*)(ws + off); off += (size_t)TSTEPS * FOURH * 4;     // 33.5 MB
  unsigned long long* pair_enc = (unsigned long long*)(ws + off); off += (size_t)TSTEPS * H * 8;  // 16.8 MB
  unsigned long long* pair_dec = (unsigned long long*)(ws + off); off += (size_t)TSTEPS * H * 8;  // 16.8 MB
  float* enc_c = (float*)(ws + off);    off += (size_t)H * 4;
  float* hs    = (float*)(ws + off);    off += (size_t)TSTEPS * H * 4;         // 8.4 MB

  // 1. embedding gathers
  gather_k<<<dim3(TSTEPS, 2), 128, 0, stream>>>(e1, gt, emb_i, emb_o, enc_embs, dec_embs);
  // 2. encoder x_gates: [2048,512] @ [4096,512]^T + (bih+bhh)
  gemm_bt<<<dim3(FOURH / 64, TSTEPS / 64), 256, 0, stream>>>(
      enc_embs, enc_Wih, enc_bih, enc_bhh, xg_enc, TSTEPS, FOURH, EM);
  // 3. encoder recurrence -> enc_c
  lstm_k<<<NWG, 256, 0, stream>>>(xg_enc, enc_Whh, nullptr, pair_enc, nullptr, enc_c);
  // 4. decoder x_gates
  gemm_bt<<<dim3(FOURH / 64, TSTEPS / 64), 256, 0, stream>>>(
      dec_embs, dec_Wih, dec_bih, dec_bhh, xg_dec, TSTEPS, FOURH, EM);
  // 5. decoder recurrence -> hs
  lstm_k<<<NWG, 256, 0, stream>>>(xg_dec, dec_Whh, enc_c, pair_dec, hs, nullptr);
  // 6. logits: [2048,1024] @ [32000,1024]^T + outb
  gemm_bt<<<dim3(OSZ / 64, TSTEPS / 64), 256, 0, stream>>>(
      hs, outW, outb, nullptr, out, TSTEPS, OSZ, H);
}